// Round 9
// baseline (373.721 us; speedup 1.0000x reference)
//
#include <hip/hip_runtime.h>

// B=8, C=d=128, H=W=64, N=H*W=4096
#define NB 8
#define CD 128
#define NN 4096
#define KV 64                  // kv keys per tile
#define SCALE 0.08838834764831845f
#define L2E 1.44269504088896f
#define QSCALE (SCALE * L2E)   // fold softmax scale AND log2(e) into Q

typedef __bf16 bf16x8 __attribute__((ext_vector_type(8)));
typedef float f32x4 __attribute__((ext_vector_type(4)));

// XOR swizzles on 16B blocks within a row; involution -> same fn write & read.
__device__ __forceinline__ unsigned swz256(unsigned row, unsigned b) {
  unsigned s = b >> 4, o = b & 15u;
  unsigned sw = (s & 8u) | ((s & 7u) ^ (row & 7u));
  return row * 256u + sw * 16u + o;
}
__device__ __forceinline__ unsigned swz128(unsigned row, unsigned b) {
  unsigned s = b >> 4, o = b & 15u;
  unsigned sw = (s ^ row) & 7u;
  return row * 128u + sw * 16u + o;
}

// v_cvt_pk_bf16_f32: dst = {bf16(lo) in [15:0], bf16(hi) in [31:16]}
__device__ __forceinline__ int cvt_pk_bf16(float lo, float hi) {
  int w;
  asm("v_cvt_pk_bf16_f32 %0, %1, %2" : "=v"(w) : "v"(lo), "v"(hi));
  return w;
}

// async global->LDS, 16B/lane; LDS dest = wave-uniform base + lane*16
__device__ __forceinline__ void gload16(const __bf16* g, unsigned char* l) {
  __builtin_amdgcn_global_load_lds(
      (const __attribute__((address_space(1))) void*)g,
      (__attribute__((address_space(3))) void*)l, 16, 0, 0);
}

// ---------------------------------------------------------------------------
// Kernel 1: fused transpose + QKV projection (unchanged from v3).
// ---------------------------------------------------------------------------
__global__ __launch_bounds__(256, 2) void qkv_kernel(
    const float* __restrict__ x,
    const float* __restrict__ qw, const float* __restrict__ qb,
    const float* __restrict__ kw, const float* __restrict__ kb,
    const float* __restrict__ vw, const float* __restrict__ vb,
    __bf16* __restrict__ Qh, __bf16* __restrict__ Ql,
    __bf16* __restrict__ Kh, __bf16* __restrict__ Kl,
    __bf16* __restrict__ Vt)
{
  __shared__ __align__(16) unsigned char sm[49664];
  const int tid = threadIdx.x;
  const int lane = tid & 63, wv = tid >> 6;
  const int l15 = lane & 15, g = lane >> 4;
  const int b = blockIdx.x & 7;
  const int n0 = (blockIdx.x >> 3) * 64;
  const f32x4 Z4 = {0.f, 0.f, 0.f, 0.f};

  #pragma unroll 4
  for (int i = 0; i < 32; ++i) {
    int e = i * 256 + tid;
    int nl = e & 63, c = e >> 6;
    float f = x[((size_t)(b * CD + c)) * NN + n0 + nl];
    __bf16 h = (__bf16)f;
    __bf16 lo = (__bf16)(f - (float)h);
    unsigned off = swz256((unsigned)nl, (unsigned)(c * 2));
    *(__bf16*)(sm + off) = h;
    *(__bf16*)(sm + 16384 + off) = lo;
  }
  __syncthreads();

  bf16x8 ah[4], al[4];
  #pragma unroll
  for (int kk = 0; kk < 4; ++kk) {
    unsigned off = swz256((unsigned)(wv * 16 + l15), (unsigned)(kk * 64 + g * 16));
    ah[kk] = *(const bf16x8*)(sm + off);
    al[kk] = *(const bf16x8*)(sm + 16384 + off);
  }

  for (int mat = 0; mat < 2; ++mat) {
    const float* gw = mat ? kw : qw;
    const float* gb = mat ? kb : qb;
    __bf16* Oh = mat ? Kh : Qh;
    __bf16* Ol = mat ? Kl : Ql;
    const float sc = mat ? 1.0f : QSCALE;
    for (int qd = 0; qd < 4; ++qd) {
      #pragma unroll 4
      for (int i = 0; i < 16; ++i) {
        int e = i * 256 + tid;
        int dl = e & 31, c = e >> 5;
        float f = gw[c * CD + qd * 32 + dl];
        __bf16 h = (__bf16)f;
        __bf16 lo = (__bf16)(f - (float)h);
        unsigned off = swz256((unsigned)dl, (unsigned)(c * 2));
        *(__bf16*)(sm + 32768 + off) = h;
        *(__bf16*)(sm + 40960 + off) = lo;
      }
      __syncthreads();
      #pragma unroll
      for (int fr = 0; fr < 2; ++fr) {
        f32x4 acc = Z4;
        #pragma unroll
        for (int kk = 0; kk < 4; ++kk) {
          unsigned off = swz256((unsigned)(fr * 16 + l15), (unsigned)(kk * 64 + g * 16));
          bf16x8 bh = *(const bf16x8*)(sm + 32768 + off);
          bf16x8 bl = *(const bf16x8*)(sm + 40960 + off);
          acc = __builtin_amdgcn_mfma_f32_16x16x32_bf16(ah[kk], bh, acc, 0, 0, 0);
          acc = __builtin_amdgcn_mfma_f32_16x16x32_bf16(ah[kk], bl, acc, 0, 0, 0);
          acc = __builtin_amdgcn_mfma_f32_16x16x32_bf16(al[kk], bh, acc, 0, 0, 0);
        }
        const int dout = qd * 32 + fr * 16 + l15;
        const float bias = gb[dout];
        #pragma unroll
        for (int r = 0; r < 4; ++r) {
          int row = n0 + wv * 16 + g * 4 + r;
          float v = (acc[r] + bias) * sc;
          __bf16 h = (__bf16)v;
          __bf16 lo = (__bf16)(v - (float)h);
          size_t go = ((size_t)(b * NN + row)) * CD + dout;
          Oh[go] = h;
          Ol[go] = lo;
        }
      }
      __syncthreads();
    }
  }

  f32x4 accV[8];
  #pragma unroll
  for (int i = 0; i < 8; ++i) accV[i] = Z4;
  for (int qd = 0; qd < 4; ++qd) {
    #pragma unroll 4
    for (int i = 0; i < 16; ++i) {
      int e = i * 256 + tid;
      int dl = e & 31, c = e >> 5;
      float f = vw[c * CD + qd * 32 + dl];
      *(__bf16*)(sm + 32768 + swz256((unsigned)dl, (unsigned)(c * 2))) = (__bf16)f;
    }
    __syncthreads();
    #pragma unroll
    for (int fr = 0; fr < 2; ++fr) {
      f32x4 acc = accV[qd * 2 + fr];
      #pragma unroll
      for (int kk = 0; kk < 4; ++kk) {
        unsigned off = swz256((unsigned)(fr * 16 + l15), (unsigned)(kk * 64 + g * 16));
        bf16x8 bh = *(const bf16x8*)(sm + 32768 + off);
        acc = __builtin_amdgcn_mfma_f32_16x16x32_bf16(ah[kk], bh, acc, 0, 0, 0);
      }
      accV[qd * 2 + fr] = acc;
    }
    __syncthreads();
  }
  #pragma unroll
  for (int df = 0; df < 8; ++df) {
    int dout = df * 16 + l15;
    float bias = vb[dout];
    #pragma unroll
    for (int r = 0; r < 4; ++r) {
      int row = wv * 16 + g * 4 + r;
      *(__bf16*)(sm + 32768 + (row * 132 + dout) * 2) = (__bf16)(accV[df][r] + bias);
    }
  }
  __syncthreads();
  #pragma unroll 4
  for (int i = 0; i < 32; ++i) {
    int e = i * 256 + tid;
    int nl = e & 63, dout = e >> 6;
    __bf16 v = *(const __bf16*)(sm + 32768 + (nl * 132 + dout) * 2);
    Vt[((size_t)(b * CD + dout)) * NN + n0 + nl] = v;
  }
}

// ---------------------------------------------------------------------------
// Kernel 2: flash attention v7.
//  128-thread blocks (2 waves), 32 q-rows/wave via 2 slabs that SHARE every
//  K and V LDS read (halves LDS reads per q-row).  K hi/lo double-buffered,
//  staged by global_load_lds (inverse-swizzled source, linear dest) -- no
//  ds_writes, no staging VGPRs for K.  V reg-staged (8 b128).  Row-sum is
//  in-lane (replaces ones-MFMA).  LDS 80KB -> 2 blocks/CU.
// ---------------------------------------------------------------------------
__global__ __launch_bounds__(128, 1) void attn_kernel(
    const __bf16* __restrict__ Qh, const __bf16* __restrict__ Ql,
    const __bf16* __restrict__ Kh, const __bf16* __restrict__ Kl,
    const __bf16* __restrict__ Vt, const float* __restrict__ x,
    const float* __restrict__ pw, const float* __restrict__ pb,
    float* __restrict__ out)
{
  // loop: KH dbuf:[0,32768) KL dbuf:[32768,65536) V:[65536,81920)
  // epilogue: O:[0,16384)  PWT:[16384,49152)
  __shared__ __align__(16) unsigned char sm[81920];
  const int tid = threadIdx.x;
  const int lane = tid & 63, wv = tid >> 6;       // wv in {0,1}
  const int l15 = lane & 15, g = lane >> 4;
  const int b = blockIdx.x & 7;           // batch -> XCD (round-robin dispatch)
  const int q0 = (blockIdx.x >> 3) * 64;
  const f32x4 Z4 = {0.f, 0.f, 0.f, 0.f};

  // Q fragments (hi/lo) for 2 slabs: q-row = q0 + wv*32 + s*16 + l15
  bf16x8 qh[2][4], ql[2][4];
  #pragma unroll
  for (int s = 0; s < 2; ++s) {
    #pragma unroll
    for (int kk = 0; kk < 4; ++kk) {
      size_t off = ((size_t)(b * NN + q0 + wv * 32 + s * 16 + l15)) * CD +
                   kk * 32 + g * 8;
      qh[s][kk] = *(const bf16x8*)(Qh + off);
      ql[s][kk] = *(const bf16x8*)(Ql + off);
    }
  }

  f32x4 accO[2][8];
  #pragma unroll
  for (int s = 0; s < 2; ++s)
    #pragma unroll
    for (int i = 0; i < 8; ++i) accO[s][i] = Z4;
  float mrow[2] = {-__builtin_inff(), -__builtin_inff()};
  float lsum[2] = {0.f, 0.f};

  const __bf16* bKh = Kh + (size_t)(b * NN) * CD;
  const __bf16* bKl = Kl + (size_t)(b * NN) * CD;
  const __bf16* bVt = Vt + (size_t)(b * CD) * NN;

  // V reg staging: 8 b128/thread
  bf16x8 pvv[8];
  const int rV = tid >> 3, sV = tid & 7;
  int offV[8];
  #pragma unroll
  for (int i = 0; i < 8; ++i) offV[i] = (i * 16 + rV) * NN + sV * 8;

  // K gload: wave wv stages rows wv*32 + i*4 + (lane>>4), slot lane&15,
  // source block inverse-swizzled (involution == swz256's).
  const int rKl = lane >> 4, sKd = lane & 15;

  const int baseAddr = ((g & 1) * 32 + l15) * 4;
  const int addrA = (g * 4) * 4;
  const int addrL = ((lane & 48) * 4);   // +q*4 at use site

  #define GLOAD_K(KT, BUF)                                                     \
    {                                                                          \
      _Pragma("unroll")                                                        \
      for (int i = 0; i < 8; ++i) {                                            \
        int r_ = wv * 32 + i * 4 + rKl;                                        \
        int ss_ = (sKd & 8) | ((sKd & 7) ^ (r_ & 7));                          \
        size_t goff_ = (size_t)((KT) * KV + r_) * CD + ss_ * 8;                \
        unsigned lb_ = (unsigned)((BUF) * 16384 + (wv * 32 + i * 4) * 256);    \
        gload16(bKh + goff_, sm + lb_);                                        \
        gload16(bKl + goff_, sm + 32768 + lb_);                                \
      }                                                                        \
    }
  #define ISSUE_V(KT)                                                          \
    {                                                                          \
      _Pragma("unroll")                                                        \
      for (int i = 0; i < 8; ++i)                                              \
        pvv[i] = *(const bf16x8*)(bVt + (KT) * KV + offV[i]);                  \
    }
  #define COMMIT_V()                                                           \
    {                                                                          \
      _Pragma("unroll")                                                        \
      for (int i = 0; i < 8; ++i)                                              \
        *(bf16x8*)(sm + 65536 +                                                \
                   swz128((unsigned)(i * 16 + rV), (unsigned)(sV * 16))) = pvv[i]; \
    }

  GLOAD_K(0, 0);
  ISSUE_V(0);
  COMMIT_V();
  __syncthreads();              // drains vmcnt: K(0) in LDS, V(0) committed

  for (int kt = 0; kt < 64; ++kt) {
    const int cur = kt & 1;
    if (kt < 63) {
      GLOAD_K(kt + 1, cur ^ 1);   // DMA flies under this tile's compute
      ISSUE_V(kt + 1);
    }
    __builtin_amdgcn_sched_barrier(0);

    // S^T = K * Q^T (swapped); K fragments read ONCE, feed both slabs.
    f32x4 s4[2][4];
    #pragma unroll
    for (int s = 0; s < 2; ++s)
      #pragma unroll
      for (int kf = 0; kf < 4; ++kf) s4[s][kf] = Z4;
    __builtin_amdgcn_s_setprio(1);
    #pragma unroll
    for (int kf = 0; kf < 4; ++kf) {
      #pragma unroll
      for (int kk = 0; kk < 4; ++kk) {
        unsigned off = (unsigned)(cur * 16384) +
                       swz256((unsigned)(kf * 16 + l15), (unsigned)(kk * 64 + g * 16));
        bf16x8 bh = *(const bf16x8*)(sm + off);
        bf16x8 bl = *(const bf16x8*)(sm + 32768 + off);
        #pragma unroll
        for (int s = 0; s < 2; ++s) {
          s4[s][kf] = __builtin_amdgcn_mfma_f32_16x16x32_bf16(bh, qh[s][kk], s4[s][kf], 0, 0, 0);
          s4[s][kf] = __builtin_amdgcn_mfma_f32_16x16x32_bf16(bl, qh[s][kk], s4[s][kf], 0, 0, 0);
          s4[s][kf] = __builtin_amdgcn_mfma_f32_16x16x32_bf16(bh, ql[s][kk], s4[s][kf], 0, 0, 0);
        }
      }
    }
    __builtin_amdgcn_s_setprio(0);

    // per-slab softmax + in-register transpose to PV A-fragments
    bf16x8 pa[2][2];
    #pragma unroll
    for (int s = 0; s < 2; ++s) {
      float mx = fmaxf(fmaxf(s4[s][0][0], s4[s][0][1]),
                       fmaxf(s4[s][0][2], s4[s][0][3]));
      #pragma unroll
      for (int kf = 1; kf < 4; ++kf)
        mx = fmaxf(mx, fmaxf(fmaxf(s4[s][kf][0], s4[s][kf][1]),
                             fmaxf(s4[s][kf][2], s4[s][kf][3])));
      mx = fmaxf(mx, __shfl_xor(mx, 16));
      mx = fmaxf(mx, __shfl_xor(mx, 32));
      const float mn = fmaxf(mrow[s], mx);
      float ps = 0.f;
      #pragma unroll
      for (int kf = 0; kf < 4; ++kf) {
        #pragma unroll
        for (int r = 0; r < 4; ++r) {
          float p = exp2f(s4[s][kf][r] - mn);
          s4[s][kf][r] = p;
          ps += p;
        }
      }
      ps += __shfl_xor(ps, 16);
      ps += __shfl_xor(ps, 32);
      const float alpha = exp2f(mrow[s] - mn);
      lsum[s] = lsum[s] * alpha + ps;
      mrow[s] = mn;

      // rescale accO rows (alpha of q=g*4+r fetched from lane g*4+r)
      int aw = __builtin_bit_cast(int, alpha);
      #pragma unroll
      for (int r = 0; r < 4; ++r) {
        float ar = __builtin_bit_cast(float,
                     __builtin_amdgcn_ds_bpermute(addrA + r * 4, aw));
        #pragma unroll
        for (int df = 0; df < 8; ++df) accO[s][df][r] *= ar;
      }

      // transpose P -> bf16 A-fragments (v5 pattern)
      int c01[4], c23[4];
      #pragma unroll
      for (int kf = 0; kf < 4; ++kf) {
        c01[kf] = cvt_pk_bf16(s4[s][kf][0], s4[s][kf][1]);
        c23[kf] = cvt_pk_bf16(s4[s][kf][2], s4[s][kf][3]);
      }
      #pragma unroll
      for (int kk2 = 0; kk2 < 2; ++kk2) {
        int w[4];
        #pragma unroll
        for (int wi = 0; wi < 4; ++wi) {
          int se = (wi & 1) ? c23[kk2 * 2] : c01[kk2 * 2];
          int so = (wi & 1) ? c23[kk2 * 2 + 1] : c01[kk2 * 2 + 1];
          int a = baseAddr + (wi >> 1) * 64;
          int ve = __builtin_amdgcn_ds_bpermute(a, se);
          int vo = __builtin_amdgcn_ds_bpermute(a, so);
          w[wi] = (g < 2) ? ve : vo;
        }
        int4 wv4 = {w[0], w[1], w[2], w[3]};
        pa[s][kk2] = __builtin_bit_cast(bf16x8, wv4);
      }
    }

    // O += P * V ; each V fragment read once, feeds both slabs
    __builtin_amdgcn_s_setprio(1);
    #pragma unroll
    for (int df = 0; df < 8; ++df) {
      #pragma unroll
      for (int kk2 = 0; kk2 < 2; ++kk2) {
        bf16x8 bv = *(const bf16x8*)(sm + 65536 +
                      swz128((unsigned)(df * 16 + l15), (unsigned)(kk2 * 64 + g * 16)));
        #pragma unroll
        for (int s = 0; s < 2; ++s)
          accO[s][df] = __builtin_amdgcn_mfma_f32_16x16x32_bf16(pa[s][kk2], bv, accO[s][df], 0, 0, 0);
      }
    }
    __builtin_amdgcn_s_setprio(0);

    __syncthreads();             // reads done; vmcnt drained (K t+1 landed)
    if (kt < 63) COMMIT_V();
    __syncthreads();
  }
  #undef GLOAD_K
  #undef ISSUE_V
  #undef COMMIT_V

  // epilogue: per-row 1/l via bpermute, O -> bf16 LDS, proj + bias + residual
  float rl[2][4];
  #pragma unroll
  for (int s = 0; s < 2; ++s) {
    int lw = __builtin_bit_cast(int, lsum[s]);
    #pragma unroll
    for (int r = 0; r < 4; ++r) {
      float lv = __builtin_bit_cast(float,
                   __builtin_amdgcn_ds_bpermute(addrL + (g * 4 + r) * 4, lw));
      rl[s][r] = 1.0f / lv;
    }
  }
  #pragma unroll
  for (int s = 0; s < 2; ++s) {
    #pragma unroll
    for (int df = 0; df < 8; ++df) {
      #pragma unroll
      for (int r = 0; r < 4; ++r) {
        unsigned row = (unsigned)(wv * 32 + s * 16 + g * 4 + r);
        *(__bf16*)(sm + swz256(row, (unsigned)((df * 16 + l15) * 2))) =
            (__bf16)(accO[s][df][r] * rl[s][r]);
      }
    }
  }
  #pragma unroll 4
  for (int i = 0; i < 32; ++i) {  // pwT[dout][c] bf16 at 16384 (128 threads)
    int e = i * 128 + tid;
    int c = e >> 5, d4 = e & 31;
    const float4 w4 = *(const float4*)(pw + c * CD + d4 * 4);
    *(__bf16*)(sm + 16384 + swz256((unsigned)(d4 * 4 + 0), (unsigned)(c * 2))) = (__bf16)w4.x;
    *(__bf16*)(sm + 16384 + swz256((unsigned)(d4 * 4 + 1), (unsigned)(c * 2))) = (__bf16)w4.y;
    *(__bf16*)(sm + 16384 + swz256((unsigned)(d4 * 4 + 2), (unsigned)(c * 2))) = (__bf16)w4.z;
    *(__bf16*)(sm + 16384 + swz256((unsigned)(d4 * 4 + 3), (unsigned)(c * 2))) = (__bf16)w4.w;
  }
  __syncthreads();

  bf16x8 oa[2][4];
  #pragma unroll
  for (int s = 0; s < 2; ++s)
    #pragma unroll
    for (int kk = 0; kk < 4; ++kk)
      oa[s][kk] = *(const bf16x8*)(sm +
                    swz256((unsigned)(wv * 32 + s * 16 + l15),
                           (unsigned)(kk * 64 + g * 16)));
  #pragma unroll
  for (int df = 0; df < 8; ++df) {
    f32x4 acc2[2] = {Z4, Z4};
    #pragma unroll
    for (int kk = 0; kk < 4; ++kk) {
      bf16x8 bw = *(const bf16x8*)(sm + 16384 +
                    swz256((unsigned)(df * 16 + l15), (unsigned)(kk * 64 + g * 16)));
      #pragma unroll
      for (int s = 0; s < 2; ++s)
        acc2[s] = __builtin_amdgcn_mfma_f32_16x16x32_bf16(oa[s][kk], bw, acc2[s], 0, 0, 0);
    }
    const int cc = df * 16 + l15;
    const float bias = pb[cc];
    #pragma unroll
    for (int s = 0; s < 2; ++s) {
      #pragma unroll
      for (int r = 0; r < 4; ++r) {
        int row = q0 + wv * 32 + s * 16 + g * 4 + r;
        float val = acc2[s][r] + bias + x[((size_t)(b * CD + cc)) * NN + row];
        out[((size_t)(b * NN + row)) * CD + cc] = val;
      }
    }
  }
}

// ---------------------------------------------------------------------------
extern "C" void kernel_launch(void* const* d_in, const int* in_sizes, int n_in,
                              void* d_out, int out_size, void* d_ws, size_t ws_size,
                              hipStream_t stream) {
  (void)in_sizes; (void)n_in; (void)out_size; (void)ws_size;
  const float* x  = (const float*)d_in[0];
  const float* qw = (const float*)d_in[1];
  const float* qb = (const float*)d_in[2];
  const float* kw = (const float*)d_in[3];
  const float* kb = (const float*)d_in[4];
  const float* vw = (const float*)d_in[5];
  const float* vb = (const float*)d_in[6];
  const float* pw = (const float*)d_in[7];
  const float* pb = (const float*)d_in[8];
  float* out = (float*)d_out;

  const size_t SZ = (size_t)NB * NN * CD;  // 4.19M elems per buffer
  __bf16* Qh = (__bf16*)d_ws;              // ws usage: 5 * 8.39 MB = 41.9 MB
  __bf16* Ql = Qh + SZ;
  __bf16* Kh = Ql + SZ;
  __bf16* Kl = Kh + SZ;
  __bf16* Vt = Kl + SZ;

  qkv_kernel<<<dim3(512), dim3(256), 0, stream>>>(x, qw, qb, kw, kb, vw, vb,
                                                  Qh, Ql, Kh, Kl, Vt);
  attn_kernel<<<dim3(512), dim3(128), 0, stream>>>(Qh, Ql, Kh, Kl, Vt, x,
                                                   pw, pb, out);
}